// Round 8
// baseline (738.161 us; speedup 1.0000x reference)
//
#include <hip/hip_runtime.h>

// GAT layer, N=8192, H=4, d=128.
// softmax_j(src_i + tgt_j) masked == adj-normalized w_j = exp(tgt_j); src cancels:
//   out[i,d] = 0.25 * sum_h ( (adj @ (w_h*ht_h))[i,d] / (adj @ w_h)[i] )
// Pipeline:
//   k0: Wt = W^T
//   k1: HT = leakyrelu(h @ W) bf16 MFMA        [8192 x 512]
//   k2: build Yt bf16 [528][8192]
//   k3: adj_gemm: 64x256 tile, 4 waves of 64x64 (acc 4x4 = 64 AGPR ->
//       ~3 waves/SIMD). BK=64 (32 MFMA/wave/barrier). adj int32->bf16
//       in-loop. XOR-swizzled LDS (slot = oct ^ (row&7)) -> 2-way banks
//       on all ds_read_b128, GLD16-compatible (swizzle on GLOBAL source).
//       grid (2 cb, 128 rb, 4 kh), cb fastest for L3 adj dedupe.
//   k4: out = 0.25 * sum_g (sum_kh C_kh)[i,512g+d] / (sum_kh S_kh)[g,i]
// ws ~83 MB: Wt 0.5M | HT 8M | Yt 8.65M | C 64M (4x16M) | S 0.5M

typedef unsigned short u16;
typedef unsigned int u32;
using bf16x8 = __attribute__((ext_vector_type(8))) short;
using f32x4  = __attribute__((ext_vector_type(4))) float;

typedef const void __attribute__((address_space(1))) gas_void;
typedef void __attribute__((address_space(3))) las_void;
#define GLD16(g, l) __builtin_amdgcn_global_load_lds((gas_void*)(g), (las_void*)(l), 16, 0, 0)

__device__ __forceinline__ u16 f2bf(float f) {
  u32 u = __float_as_uint(f);
  return (u16)((u + 0x7FFFu + ((u >> 16) & 1u)) >> 16);  // RNE
}
__device__ __forceinline__ float bf2f(u16 u) {
  return __uint_as_float(((u32)u) << 16);
}

// ---------------- k0: transpose W [256][512] -> Wt [512][256] ----------------
__global__ void transpose_w(const float* __restrict__ W, float* __restrict__ Wt) {
  __shared__ float tile[32][33];
  int cb = blockIdx.x * 32, kb = blockIdx.y * 32;
  int tc = threadIdx.x & 31, tr = threadIdx.x >> 5;
  for (int p = 0; p < 32; p += 8)
    tile[tr + p][tc] = W[(size_t)(kb + tr + p) * 512 + cb + tc];
  __syncthreads();
  for (int p = 0; p < 32; p += 8)
    Wt[(size_t)(cb + tr + p) * 256 + kb + tc] = tile[tc][tr + p];
}

// ---------------- k1: HT = leaky(h @ W), bf16 out [8192][512] ----------------
__global__ void ht_gemm(const float* __restrict__ h, const float* __restrict__ Wt,
                        u16* __restrict__ HT) {
  __shared__ __align__(16) u16 Abuf[128 * 40];
  __shared__ __align__(16) u16 Bbuf[128 * 40];
  int tid = threadIdx.x;
  int cb = blockIdx.x, rb = blockIdx.y;
  int r0 = rb * 128, c0 = cb * 128;
  int lane = tid & 63, wv = tid >> 6;
  int wr = wv >> 1, wc = wv & 1;
  int mrow = lane & 15, q = lane >> 4;
  int ch = tid & 7, m0 = tid >> 3;

  f32x4 acc[4][4];
#pragma unroll
  for (int i = 0; i < 4; i++)
#pragma unroll
    for (int j = 0; j < 4; j++) acc[i][j] = f32x4{0.f, 0.f, 0.f, 0.f};

  for (int kt = 0; kt < 256; kt += 32) {
    __syncthreads();
#pragma unroll
    for (int mp = 0; mp < 128; mp += 32) {
      int m = m0 + mp;
      float4 v = *(const float4*)(&h[(size_t)(r0 + m) * 256 + kt + ch * 4]);
      uint2 p;
      p.x = (u32)f2bf(v.x) | ((u32)f2bf(v.y) << 16);
      p.y = (u32)f2bf(v.z) | ((u32)f2bf(v.w) << 16);
      *(uint2*)(&Abuf[m * 40 + ch * 4]) = p;
      float4 u = *(const float4*)(&Wt[(size_t)(c0 + m) * 256 + kt + ch * 4]);
      uint2 r;
      r.x = (u32)f2bf(u.x) | ((u32)f2bf(u.y) << 16);
      r.y = (u32)f2bf(u.z) | ((u32)f2bf(u.w) << 16);
      *(uint2*)(&Bbuf[m * 40 + ch * 4]) = r;
    }
    __syncthreads();
    bf16x8 af[4], bfv[4];
#pragma unroll
    for (int i = 0; i < 4; i++)
      af[i] = *(const bf16x8*)(&Abuf[(wr * 64 + i * 16 + mrow) * 40 + q * 8]);
#pragma unroll
    for (int j = 0; j < 4; j++)
      bfv[j] = *(const bf16x8*)(&Bbuf[(wc * 64 + j * 16 + mrow) * 40 + q * 8]);
#pragma unroll
    for (int i = 0; i < 4; i++)
#pragma unroll
      for (int j = 0; j < 4; j++)
        acc[i][j] = __builtin_amdgcn_mfma_f32_16x16x32_bf16(af[i], bfv[j], acc[i][j], 0, 0, 0);
  }
#pragma unroll
  for (int i = 0; i < 4; i++)
#pragma unroll
    for (int j = 0; j < 4; j++)
#pragma unroll
      for (int r = 0; r < 4; r++) {
        int gi = r0 + wr * 64 + i * 16 + q * 4 + r;
        int gc = c0 + wc * 64 + j * 16 + mrow;
        float v = acc[i][j][r];
        v = v >= 0.f ? v : 0.1f * v;
        HT[(size_t)gi * 512 + gc] = f2bf(v);
      }
}

// ---------------- k2: build Yt [528][8192] bf16 ----------------
__global__ void build_yt(const u16* __restrict__ HT, const float* __restrict__ a,
                         u16* __restrict__ Yt) {
  __shared__ u16 sht[64][528];
  __shared__ float swv[64 * 4];
  __shared__ float sa[512];
  int t = threadIdx.x;
  int j0 = blockIdx.x * 64;
  for (int i = t; i < 512; i += 256) {
    int g = i >> 7, d = i & 127;
    sa[i] = a[g * 256 + 128 + d];
  }
#pragma unroll
  for (int p = 0; p < 16; ++p) {
    int el = t + 256 * p;
    int row = el >> 6, col8 = el & 63;
    *(uint4*)(&sht[row][col8 * 8]) = *(const uint4*)(&HT[(size_t)(j0 + row) * 512 + col8 * 8]);
  }
  __syncthreads();
  {
    int jl = t >> 2, g = t & 3;
    float acc = 0.f;
#pragma unroll
    for (int d8 = 0; d8 < 16; ++d8) {
      bf16x8 v = *(const bf16x8*)(&sht[jl][g * 128 + d8 * 8]);
#pragma unroll
      for (int u = 0; u < 8; ++u)
        acc += bf2f((u16)v[u]) * sa[g * 128 + d8 * 8 + u];
    }
    swv[jl * 4 + g] = __expf(acc);
  }
  __syncthreads();
  int oj = (t & 7) * 8, oc = t >> 3;
  for (int pass = 0; pass < 17; ++pass) {
    int c = pass * 32 + oc;
    if (c >= 528) break;
    u32 pk[4] = {0u, 0u, 0u, 0u};
    if (c < 512) {
      int g = c >> 7;
#pragma unroll
      for (int u = 0; u < 4; ++u) {
        int j = oj + 2 * u;
        float v0 = bf2f(sht[j][c]) * swv[j * 4 + g];
        float v1 = bf2f(sht[j + 1][c]) * swv[(j + 1) * 4 + g];
        pk[u] = (u32)f2bf(v0) | ((u32)f2bf(v1) << 16);
      }
    } else if (c < 516) {
      int g = c - 512;
#pragma unroll
      for (int u = 0; u < 4; ++u) {
        int j = oj + 2 * u;
        float v0 = swv[j * 4 + g];
        float v1 = swv[(j + 1) * 4 + g];
        pk[u] = (u32)f2bf(v0) | ((u32)f2bf(v1) << 16);
      }
    }
    *(uint4*)(&Yt[(size_t)c * 8192 + j0 + oj]) = make_uint4(pk[0], pk[1], pk[2], pk[3]);
  }
}

// ---------------- k3: adj GEMM, 64x256 tile, BK=64, swizzled LDS ----------------
// grid (2 cb, 128 rb, 4 kh), 256 threads = 4 waves (wc 0..3), wave 64x64.
// LDS row stride 64 u16 (8 octets); octet slot s of row m holds global
// octet s ^ (m&7)  -> all b128 reads/writes 2-way bank aliased (free).
// C_kh [8192][512], S_kh [4][8192] written directly (no atomics).
__global__ __launch_bounds__(256) void adj_gemm(const int* __restrict__ adj,
                                                const u16* __restrict__ Yt,
                                                float* __restrict__ C,
                                                float* __restrict__ S) {
  __shared__ __align__(16) u16 Abuf[64 * 64];    // 8 KB
  __shared__ __align__(16) u16 Bbuf[256 * 64];   // 32 KB
  __shared__ __align__(16) u16 Bden[16 * 64];    // 2 KB
  int tid = threadIdx.x;
  int cb = blockIdx.x, rb = blockIdx.y, kh = blockIdx.z;
  int r0 = rb * 64, c0 = cb * 256, k0 = kh * 2048, kend = k0 + 2048;
  int lane = tid & 63, wv = tid >> 6;  // wv == wc (column band)
  int mrow = lane & 15, q = lane >> 4;
  // A staging: thread -> (row tid>>2, slots {tid&3, (tid&3)+4})
  int am = tid >> 2, as0 = tid & 3;
  // B staging (GLD16): call covers 8 rows x 8 octets; lane -> (row l>>3, slot l&7)
  int brow = lane >> 3, bs = lane & 7;
  int bo = bs ^ (brow & 7);  // swizzled global octet
  bool do_den = (cb == 0) && (wv == 0);

  f32x4 acc[4][4];
#pragma unroll
  for (int i = 0; i < 4; i++)
#pragma unroll
    for (int j = 0; j < 4; j++) acc[i][j] = f32x4{0.f, 0.f, 0.f, 0.f};
  f32x4 accD[2];
  accD[0] = f32x4{0.f, 0.f, 0.f, 0.f};
  accD[1] = f32x4{0.f, 0.f, 0.f, 0.f};

  for (int kt = k0; kt < kend; kt += 64) {
    __syncthreads();
    // A: 64 rows x 64 k, int32 -> bf16, 2 swizzled octet-slots per thread
#pragma unroll
    for (int p = 0; p < 2; ++p) {
      int s = as0 + p * 4;
      int o = s ^ (am & 7);
      const int* ap = &adj[(size_t)(r0 + am) * 8192 + kt + o * 8];
      int4 v0 = *(const int4*)(ap);
      int4 v1 = *(const int4*)(ap + 4);
      uint4 pk;  // {0,1} -> bf16 bits 0x3F80*x, packed pairwise
      pk.x = 16256u * ((u32)v0.x | ((u32)v0.y << 16));
      pk.y = 16256u * ((u32)v0.z | ((u32)v0.w << 16));
      pk.z = 16256u * ((u32)v1.x | ((u32)v1.y << 16));
      pk.w = 16256u * ((u32)v1.z | ((u32)v1.w << 16));
      *(uint4*)(&Abuf[am * 64 + s * 8]) = pk;
    }
    // B: 256 rows x 64 k via GLD16, 8 calls/wave (8 rows each), swizzled src
#pragma unroll
    for (int p = 0; p < 8; ++p) {
      int g0 = (wv * 8 + p) * 8;  // base row of this 8-row group
      GLD16(&Yt[(size_t)(c0 + g0 + brow) * 8192 + kt + bo * 8], &Bbuf[g0 * 64]);
    }
    if (do_den) {
      GLD16(&Yt[(size_t)(512 + brow) * 8192 + kt + bo * 8], &Bden[0]);
      GLD16(&Yt[(size_t)(520 + brow) * 8192 + kt + bo * 8], &Bden[8 * 64]);
    }
    __syncthreads();
    // two K=32 chunks
#pragma unroll
    for (int c = 0; c < 2; ++c) {
      int sq = ((c * 4 + q) ^ (mrow & 7)) * 8;  // swizzled slot offset
      bf16x8 af[4], bfv[4];
#pragma unroll
      for (int i = 0; i < 4; i++)
        af[i] = *(const bf16x8*)(&Abuf[(i * 16 + mrow) * 64 + sq]);
#pragma unroll
      for (int j = 0; j < 4; j++)
        bfv[j] = *(const bf16x8*)(&Bbuf[(wv * 64 + j * 16 + mrow) * 64 + sq]);
#pragma unroll
      for (int i = 0; i < 4; i++)
#pragma unroll
        for (int j = 0; j < 4; j++)
          acc[i][j] = __builtin_amdgcn_mfma_f32_16x16x32_bf16(af[i], bfv[j], acc[i][j], 0, 0, 0);
      if (do_den) {
        bf16x8 bd = *(const bf16x8*)(&Bden[mrow * 64 + sq]);
#pragma unroll
        for (int i = 0; i < 4; i++) {
          bf16x8 a2 = *(const bf16x8*)(&Abuf[(i * 16 + mrow) * 64 + sq]);
          accD[c] = __builtin_amdgcn_mfma_f32_16x16x32_bf16(a2, bd, accD[c], 0, 0, 0);
        }
      }
    }
  }
  float* Ck = C + (size_t)kh * 8192 * 512;
#pragma unroll
  for (int i = 0; i < 4; i++)
#pragma unroll
    for (int j = 0; j < 4; j++)
#pragma unroll
      for (int r = 0; r < 4; r++) {
        int gi = r0 + i * 16 + q * 4 + r;
        int gc = c0 + wv * 64 + j * 16 + mrow;
        Ck[(size_t)gi * 512 + gc] = acc[i][j][r];
      }
  // NOTE: accD[c] accumulated over i-tiles with shared accumulator per chunk:
  // accD[0]+accD[1] holds, for each (mrow<4, q, r): sum over rows of tile?? --
  // careful: accD uses same 16x16x32 shape; i-loop reuses accD[c], so
  // accD[c][r] at (mrow,q) = sum_i (adj_tile_i @ w)[...]. That is WRONG unless
  // each i wrote a distinct row range. It does NOT. Fix: accumulate den per i.
  if (do_den && mrow < 4) {
    // recompute-free correction is impossible here; this branch is replaced
    // below by the correct epilogue using accD2.
  }
  if (do_den && mrow < 4) {
    float* Sk = S + (size_t)kh * 4 * 8192;
    // accD was accumulated with af[i] varying but single accumulator; the
    // MFMA sums over i -> S rows would be summed across i-tiles. To keep
    // correctness we instead recompute: the den result for row block i lives
    // in acc-layout rows q*4+r of tile i. Since we cannot recover per-i
    // contributions from accD, we fall back: S is written by a dedicated
    // pass below (see den_fix kernel launched after adj_gemm).
    (void)Sk;
  }
}

// ---------------- k3b: denominators S_kh[4][8192] = adj @ w ----------------
// grid (128 rb, 4 kh), 256 thr. Each thread: 2 rows x 4 heads partial sums.
__global__ __launch_bounds__(256) void den_gemm(const int* __restrict__ adj,
                                                const u16* __restrict__ Yt,
                                                float* __restrict__ S) {
  __shared__ __align__(16) u16 Wbuf[4][2048];  // w[g][k] bf16 for this kh band
  int tid = threadIdx.x;
  int rb = blockIdx.x, kh = blockIdx.y;
  int r0 = rb * 64, k0 = kh * 2048;
  // stage w rows (4 x 2048 bf16 = 16 KB) cooperatively
#pragma unroll
  for (int p = 0; p < 4; ++p) {
    int el = tid + p * 256;     // 0..1023
    int g = el >> 8, c8 = (el & 255) * 8;
    *(uint4*)(&Wbuf[g][c8]) = *(const uint4*)(&Yt[(size_t)(512 + g) * 8192 + k0 + c8]);
  }
  __syncthreads();
  // each thread: row r = r0 + (tid>>2), head g = tid&3; quarter-row per pass
  int rr = tid >> 2, g = tid & 3;
  const int* ap = &adj[(size_t)(r0 + rr) * 8192 + k0];
  float s = 0.f;
  for (int k = 0; k < 2048; k += 4) {
    int4 v = *(const int4*)(&ap[k]);
    s += (v.x ? bf2f(Wbuf[g][k]) : 0.f) + (v.y ? bf2f(Wbuf[g][k + 1]) : 0.f) +
         (v.z ? bf2f(Wbuf[g][k + 2]) : 0.f) + (v.w ? bf2f(Wbuf[g][k + 3]) : 0.f);
  }
  S[(size_t)kh * 4 * 8192 + (size_t)g * 8192 + r0 + rr] = s;
}

// ---------------- k4: combine K-split + heads ----------------
__global__ void finalize_gat(const float* __restrict__ C, const float* __restrict__ S,
                             float* __restrict__ out) {
  int idx = blockIdx.x * 256 + threadIdx.x;
  int i = idx >> 7, d = idx & 127;
  float s = 0.f;
#pragma unroll
  for (int g = 0; g < 4; ++g) {
    float num = 0.f, den = 0.f;
#pragma unroll
    for (int kh = 0; kh < 4; ++kh) {
      num += C[(size_t)kh * 8192 * 512 + (size_t)i * 512 + g * 128 + d];
      den += S[(size_t)kh * 4 * 8192 + (size_t)g * 8192 + i];
    }
    s += num / den;
  }
  out[idx] = 0.25f * s;
}

extern "C" void kernel_launch(void* const* d_in, const int* in_sizes, int n_in,
                              void* d_out, int out_size, void* d_ws, size_t ws_size,
                              hipStream_t stream) {
  const float* h   = (const float*)d_in[0];
  const int*   adj = (const int*)d_in[1];
  const float* W   = (const float*)d_in[2];
  const float* a   = (const float*)d_in[3];
  float* out = (float*)d_out;
  char* ws = (char*)d_ws;
  // ws: Wt 0.5M | HT 8M | Yt 8.65M | C 64M (4 x 16M) | S 0.5M  (~83 MB)
  float* Wt = (float*)(ws + 0);
  u16*   HT = (u16*)(ws + 524288);
  u16*   Yt = (u16*)(ws + 8912896);
  float* C  = (float*)(ws + 17563648);
  float* S  = (float*)(ws + 84672512);

  transpose_w<<<dim3(16, 8), 256, 0, stream>>>(W, Wt);
  ht_gemm<<<dim3(4, 64), 256, 0, stream>>>(h, Wt, HT);
  build_yt<<<dim3(128), 256, 0, stream>>>(HT, a, Yt);
  adj_gemm<<<dim3(2, 128, 4), 256, 0, stream>>>(adj, Yt, C, S);
  den_gemm<<<dim3(128, 4), 256, 0, stream>>>(adj, Yt, S);
  finalize_gat<<<dim3(4096), 256, 0, stream>>>(C, S, out);
}

// Round 9
// 577.442 us; speedup vs baseline: 1.2783x; 1.2783x over previous
//
#include <hip/hip_runtime.h>

// GAT layer, N=8192, H=4, d=128.
// softmax_j(src_i + tgt_j) masked == adj-normalized w_j = exp(tgt_j); src cancels:
//   out[i,d] = 0.25 * sum_h ( (adj @ (w_h*ht_h))[i,d] / (adj @ w_h)[i] )
// Pipeline:
//   k0: Wt = W^T
//   k1: HT = leakyrelu(h @ W) bf16 MFMA        [8192 x 512]
//   k2: build Yt bf16 [528][8192]
//   k2b: pack_adj: adj int32 -> 1 bit/elem, Ap [8192][256] u32 (8 MB, L2-fits)
//   k3: adj_gemm: 64x256 tile, 4 waves of 64x64, BK=64. A = bit-expand
//       from Ap (512 B/iter instead of 16 KB int32 -> K-loop has no HBM
//       dependence). XOR-swizzled LDS (slot = oct ^ (row&7)) -> conflict-free
//       ds_read_b128, GLD16-compatible. Fused denominator with PER-ROW-TILE
//       accumulators accD[i] (r8's bug: one accumulator summed across tiles).
//       grid (2 cb, 128 rb, 4 kh); per-kh C/S buffers (no atomics).
//   k4: out = 0.25 * sum_g (sum_kh C_kh)[i,512g+d] / (sum_kh S_kh)[g,i]
// ws ~93 MB: Wt 0.5M | HT 8M | Yt 8.65M | C 64M (4x16M) | S 0.5M | Ap 8M

typedef unsigned short u16;
typedef unsigned int u32;
using bf16x8 = __attribute__((ext_vector_type(8))) short;
using f32x4  = __attribute__((ext_vector_type(4))) float;

typedef const void __attribute__((address_space(1))) gas_void;
typedef void __attribute__((address_space(3))) las_void;
#define GLD16(g, l) __builtin_amdgcn_global_load_lds((gas_void*)(g), (las_void*)(l), 16, 0, 0)

__device__ __forceinline__ u16 f2bf(float f) {
  u32 u = __float_as_uint(f);
  return (u16)((u + 0x7FFFu + ((u >> 16) & 1u)) >> 16);  // RNE
}
__device__ __forceinline__ float bf2f(u16 u) {
  return __uint_as_float(((u32)u) << 16);
}

// ---------------- k0: transpose W [256][512] -> Wt [512][256] ----------------
__global__ void transpose_w(const float* __restrict__ W, float* __restrict__ Wt) {
  __shared__ float tile[32][33];
  int cb = blockIdx.x * 32, kb = blockIdx.y * 32;
  int tc = threadIdx.x & 31, tr = threadIdx.x >> 5;
  for (int p = 0; p < 32; p += 8)
    tile[tr + p][tc] = W[(size_t)(kb + tr + p) * 512 + cb + tc];
  __syncthreads();
  for (int p = 0; p < 32; p += 8)
    Wt[(size_t)(cb + tr + p) * 256 + kb + tc] = tile[tc][tr + p];
}

// ---------------- k1: HT = leaky(h @ W), bf16 out [8192][512] ----------------
__global__ void ht_gemm(const float* __restrict__ h, const float* __restrict__ Wt,
                        u16* __restrict__ HT) {
  __shared__ __align__(16) u16 Abuf[128 * 40];
  __shared__ __align__(16) u16 Bbuf[128 * 40];
  int tid = threadIdx.x;
  int cb = blockIdx.x, rb = blockIdx.y;
  int r0 = rb * 128, c0 = cb * 128;
  int lane = tid & 63, wv = tid >> 6;
  int wr = wv >> 1, wc = wv & 1;
  int mrow = lane & 15, q = lane >> 4;
  int ch = tid & 7, m0 = tid >> 3;

  f32x4 acc[4][4];
#pragma unroll
  for (int i = 0; i < 4; i++)
#pragma unroll
    for (int j = 0; j < 4; j++) acc[i][j] = f32x4{0.f, 0.f, 0.f, 0.f};

  for (int kt = 0; kt < 256; kt += 32) {
    __syncthreads();
#pragma unroll
    for (int mp = 0; mp < 128; mp += 32) {
      int m = m0 + mp;
      float4 v = *(const float4*)(&h[(size_t)(r0 + m) * 256 + kt + ch * 4]);
      uint2 p;
      p.x = (u32)f2bf(v.x) | ((u32)f2bf(v.y) << 16);
      p.y = (u32)f2bf(v.z) | ((u32)f2bf(v.w) << 16);
      *(uint2*)(&Abuf[m * 40 + ch * 4]) = p;
      float4 u = *(const float4*)(&Wt[(size_t)(c0 + m) * 256 + kt + ch * 4]);
      uint2 r;
      r.x = (u32)f2bf(u.x) | ((u32)f2bf(u.y) << 16);
      r.y = (u32)f2bf(u.z) | ((u32)f2bf(u.w) << 16);
      *(uint2*)(&Bbuf[m * 40 + ch * 4]) = r;
    }
    __syncthreads();
    bf16x8 af[4], bfv[4];
#pragma unroll
    for (int i = 0; i < 4; i++)
      af[i] = *(const bf16x8*)(&Abuf[(wr * 64 + i * 16 + mrow) * 40 + q * 8]);
#pragma unroll
    for (int j = 0; j < 4; j++)
      bfv[j] = *(const bf16x8*)(&Bbuf[(wc * 64 + j * 16 + mrow) * 40 + q * 8]);
#pragma unroll
    for (int i = 0; i < 4; i++)
#pragma unroll
      for (int j = 0; j < 4; j++)
        acc[i][j] = __builtin_amdgcn_mfma_f32_16x16x32_bf16(af[i], bfv[j], acc[i][j], 0, 0, 0);
  }
#pragma unroll
  for (int i = 0; i < 4; i++)
#pragma unroll
    for (int j = 0; j < 4; j++)
#pragma unroll
      for (int r = 0; r < 4; r++) {
        int gi = r0 + wr * 64 + i * 16 + q * 4 + r;
        int gc = c0 + wc * 64 + j * 16 + mrow;
        float v = acc[i][j][r];
        v = v >= 0.f ? v : 0.1f * v;
        HT[(size_t)gi * 512 + gc] = f2bf(v);
      }
}

// ---------------- k2: build Yt [528][8192] bf16 ----------------
__global__ void build_yt(const u16* __restrict__ HT, const float* __restrict__ a,
                         u16* __restrict__ Yt) {
  __shared__ u16 sht[64][528];
  __shared__ float swv[64 * 4];
  __shared__ float sa[512];
  int t = threadIdx.x;
  int j0 = blockIdx.x * 64;
  for (int i = t; i < 512; i += 256) {
    int g = i >> 7, d = i & 127;
    sa[i] = a[g * 256 + 128 + d];
  }
#pragma unroll
  for (int p = 0; p < 16; ++p) {
    int el = t + 256 * p;
    int row = el >> 6, col8 = el & 63;
    *(uint4*)(&sht[row][col8 * 8]) = *(const uint4*)(&HT[(size_t)(j0 + row) * 512 + col8 * 8]);
  }
  __syncthreads();
  {
    int jl = t >> 2, g = t & 3;
    float acc = 0.f;
#pragma unroll
    for (int d8 = 0; d8 < 16; ++d8) {
      bf16x8 v = *(const bf16x8*)(&sht[jl][g * 128 + d8 * 8]);
#pragma unroll
      for (int u = 0; u < 8; ++u)
        acc += bf2f((u16)v[u]) * sa[g * 128 + d8 * 8 + u];
    }
    swv[jl * 4 + g] = __expf(acc);
  }
  __syncthreads();
  int oj = (t & 7) * 8, oc = t >> 3;
  for (int pass = 0; pass < 17; ++pass) {
    int c = pass * 32 + oc;
    if (c >= 528) break;
    u32 pk[4] = {0u, 0u, 0u, 0u};
    if (c < 512) {
      int g = c >> 7;
#pragma unroll
      for (int u = 0; u < 4; ++u) {
        int j = oj + 2 * u;
        float v0 = bf2f(sht[j][c]) * swv[j * 4 + g];
        float v1 = bf2f(sht[j + 1][c]) * swv[(j + 1) * 4 + g];
        pk[u] = (u32)f2bf(v0) | ((u32)f2bf(v1) << 16);
      }
    } else if (c < 516) {
      int g = c - 512;
#pragma unroll
      for (int u = 0; u < 4; ++u) {
        int j = oj + 2 * u;
        float v0 = swv[j * 4 + g];
        float v1 = swv[(j + 1) * 4 + g];
        pk[u] = (u32)f2bf(v0) | ((u32)f2bf(v1) << 16);
      }
    }
    *(uint4*)(&Yt[(size_t)c * 8192 + j0 + oj]) = make_uint4(pk[0], pk[1], pk[2], pk[3]);
  }
}

// ---------------- k2b: pack adj -> 1 bit/elem, Ap [8192][256] u32 ----------------
// ballot-based: each wave packs 2048 consecutive elems -> 64 words; lane w
// keeps word w (from round w>>1, half w&1). Loads perfectly coalesced.
__global__ void pack_adj(const int* __restrict__ adj, u32* __restrict__ Ap) {
  int tid = threadIdx.x;
  int lane = tid & 63, wv = tid >> 6;
  size_t wgid = (size_t)blockIdx.x * 4 + wv;
  const int* base = adj + wgid * 2048;
  u32 myword = 0;
#pragma unroll
  for (int r = 0; r < 32; ++r) {
    int v = base[r * 64 + lane];
    unsigned long long m = __ballot(v != 0);
    u32 pick = (lane & 1) ? (u32)(m >> 32) : (u32)m;
    if ((lane >> 1) == r) myword = pick;
  }
  Ap[wgid * 64 + lane] = myword;
}

// ---------------- k3: adj GEMM from packed bits, fused denominator ----------------
// grid (2 cb, 128 rb, 4 kh), 256 threads = 4 waves (wv = column band), 64x64/wave.
// LDS row stride 64 u16; octet slot s of row m holds global octet s^(m&7).
// A tile expanded from bits in-register (512 B/iter). C_kh/S_kh direct stores.
__global__ __launch_bounds__(256) void adj_gemm(const u32* __restrict__ Ap,
                                                const u16* __restrict__ Yt,
                                                float* __restrict__ C,
                                                float* __restrict__ S) {
  __shared__ __align__(16) u16 Abuf[64 * 64];    // 8 KB
  __shared__ __align__(16) u16 Bbuf[256 * 64];   // 32 KB
  __shared__ __align__(16) u16 Bden[16 * 64];    // 2 KB
  int tid = threadIdx.x;
  int cb = blockIdx.x, rb = blockIdx.y, kh = blockIdx.z;
  int r0 = rb * 64, c0 = cb * 256, k0 = kh * 2048, kend = k0 + 2048;
  int lane = tid & 63, wv = tid >> 6;  // wv == column band
  int mrow = lane & 15, q = lane >> 4;
  int am = tid >> 2, as0 = tid & 3;    // A: row tid>>2, slots {as0, as0+4}
  int brow = lane >> 3, bs = lane & 7; // B (GLD16): 8 rows x 8 octets per call
  int bo = bs ^ (brow & 7);            // swizzled global octet
  bool do_den = (cb == 0) && (wv == 0);

  f32x4 acc[4][4];
#pragma unroll
  for (int i = 0; i < 4; i++)
#pragma unroll
    for (int j = 0; j < 4; j++) acc[i][j] = f32x4{0.f, 0.f, 0.f, 0.f};
  f32x4 accD[4];
#pragma unroll
  for (int i = 0; i < 4; i++) accD[i] = f32x4{0.f, 0.f, 0.f, 0.f};

  const u32* aprow = &Ap[(size_t)(r0 + am) * 256];

  for (int kt = k0; kt < kend; kt += 64) {
    __syncthreads();
    // A: 64 rows x 64 k from bits, 2 swizzled octet-slots per thread
    {
      uint2 bits = *(const uint2*)(&aprow[kt >> 5]);
#pragma unroll
      for (int p = 0; p < 2; ++p) {
        int s = as0 + p * 4;
        int o = s ^ (am & 7);
        u32 b = (((o & 4) ? bits.y : bits.x) >> ((o & 3) * 8)) & 0xFFu;
        uint4 pk;  // bit pair -> packed bf16 {0,1}
        pk.x = ((b & 1u) ? 0x3F80u : 0u) | ((b & 2u) ? 0x3F800000u : 0u);
        pk.y = ((b & 4u) ? 0x3F80u : 0u) | ((b & 8u) ? 0x3F800000u : 0u);
        pk.z = ((b & 16u) ? 0x3F80u : 0u) | ((b & 32u) ? 0x3F800000u : 0u);
        pk.w = ((b & 64u) ? 0x3F80u : 0u) | ((b & 128u) ? 0x3F800000u : 0u);
        *(uint4*)(&Abuf[am * 64 + s * 8]) = pk;
      }
    }
    // B: 256 rows x 64 k via GLD16, 8 calls/wave (8 rows each), swizzled src
#pragma unroll
    for (int p = 0; p < 8; ++p) {
      int g0 = (wv * 8 + p) * 8;
      GLD16(&Yt[(size_t)(c0 + g0 + brow) * 8192 + kt + bo * 8], &Bbuf[g0 * 64]);
    }
    if (do_den) {
      GLD16(&Yt[(size_t)(512 + brow) * 8192 + kt + bo * 8], &Bden[0]);
      GLD16(&Yt[(size_t)(520 + brow) * 8192 + kt + bo * 8], &Bden[8 * 64]);
    }
    __syncthreads();
    // two K=32 chunks
#pragma unroll
    for (int c = 0; c < 2; ++c) {
      int sq = ((c * 4 + q) ^ (mrow & 7)) * 8;  // swizzled slot offset
      bf16x8 af[4], bfv[4];
#pragma unroll
      for (int i = 0; i < 4; i++)
        af[i] = *(const bf16x8*)(&Abuf[(i * 16 + mrow) * 64 + sq]);
#pragma unroll
      for (int j = 0; j < 4; j++)
        bfv[j] = *(const bf16x8*)(&Bbuf[(wv * 64 + j * 16 + mrow) * 64 + sq]);
#pragma unroll
      for (int i = 0; i < 4; i++)
#pragma unroll
        for (int j = 0; j < 4; j++)
          acc[i][j] = __builtin_amdgcn_mfma_f32_16x16x32_bf16(af[i], bfv[j], acc[i][j], 0, 0, 0);
      if (do_den) {
        bf16x8 bd = *(const bf16x8*)(&Bden[mrow * 64 + sq]);
#pragma unroll
        for (int i = 0; i < 4; i++)
          accD[i] = __builtin_amdgcn_mfma_f32_16x16x32_bf16(af[i], bd, accD[i], 0, 0, 0);
      }
    }
  }
  float* Ck = C + (size_t)kh * 8192 * 512;
#pragma unroll
  for (int i = 0; i < 4; i++)
#pragma unroll
    for (int j = 0; j < 4; j++)
#pragma unroll
      for (int r = 0; r < 4; r++) {
        int gi = r0 + i * 16 + q * 4 + r;
        int gc = c0 + wv * 64 + j * 16 + mrow;
        Ck[(size_t)gi * 512 + gc] = acc[i][j][r];
      }
  if (do_den && mrow < 4) {
    float* Sk = S + (size_t)kh * 4 * 8192;
#pragma unroll
    for (int i = 0; i < 4; i++)
#pragma unroll
      for (int r = 0; r < 4; r++) {
        int gi = r0 + i * 16 + q * 4 + r;
        Sk[(size_t)mrow * 8192 + gi] = accD[i][r];
      }
  }
}

// ---------------- k4: combine K-split + heads ----------------
__global__ void finalize_gat(const float* __restrict__ C, const float* __restrict__ S,
                             float* __restrict__ out) {
  int idx = blockIdx.x * 256 + threadIdx.x;
  int i = idx >> 7, d = idx & 127;
  float s = 0.f;
#pragma unroll
  for (int g = 0; g < 4; ++g) {
    float num = 0.f, den = 0.f;
#pragma unroll
    for (int kh = 0; kh < 4; ++kh) {
      num += C[(size_t)kh * 8192 * 512 + (size_t)i * 512 + g * 128 + d];
      den += S[(size_t)kh * 4 * 8192 + (size_t)g * 8192 + i];
    }
    s += num / den;
  }
  out[idx] = 0.25f * s;
}

extern "C" void kernel_launch(void* const* d_in, const int* in_sizes, int n_in,
                              void* d_out, int out_size, void* d_ws, size_t ws_size,
                              hipStream_t stream) {
  const float* h   = (const float*)d_in[0];
  const int*   adj = (const int*)d_in[1];
  const float* W   = (const float*)d_in[2];
  const float* a   = (const float*)d_in[3];
  float* out = (float*)d_out;
  char* ws = (char*)d_ws;
  // ws: Wt 0.5M | HT 8M | Yt 8.65M | C 64M (4x16M) | S 0.5M | Ap 8M (~93 MB)
  float* Wt = (float*)(ws + 0);
  u16*   HT = (u16*)(ws + 524288);
  u16*   Yt = (u16*)(ws + 8912896);
  float* C  = (float*)(ws + 17563648);
  float* S  = (float*)(ws + 84672512);
  u32*   Ap = (u32*)(ws + 85196800);

  transpose_w<<<dim3(16, 8), 256, 0, stream>>>(W, Wt);
  ht_gemm<<<dim3(4, 64), 256, 0, stream>>>(h, Wt, HT);
  build_yt<<<dim3(128), 256, 0, stream>>>(HT, a, Yt);
  pack_adj<<<dim3(8192), 256, 0, stream>>>(adj, Ap);
  adj_gemm<<<dim3(2, 128, 4), 256, 0, stream>>>(Ap, Yt, C, S);
  finalize_gat<<<dim3(4096), 256, 0, stream>>>(C, S, out);
}